// Round 4
// baseline (10301.216 us; speedup 1.0000x reference)
//
#include <hip/hip_runtime.h>
#include <hip/hip_bf16.h>

#define B_SZ   1024
#define T_SZ   128
#define H_SZ   512
#define DPV    10

// Inputs fp32, OUTPUT fp32 (reference dtype; R3's bf16-out gave the exact
// "bf16 pair re-glued as fp32" error signature). Internals: weights converted
// fp32->bf16 once, GEMMs on bf16 MFMA with fp32 accumulation, fp32 c-master.

typedef __attribute__((ext_vector_type(8))) short bfrag8;
typedef __attribute__((ext_vector_type(4))) float floatx4;

static __device__ __forceinline__ bfrag8 load8(const __hip_bfloat16* p) {
    return *(const bfrag8*)(const void*)p;  // 16B-aligned by construction
}
static __device__ __forceinline__ float sigm(float x) {
    return 1.0f / (1.0f + __expf(-x));
}

// ---------------------------------------------------------------------------
// One-time weight conversion: fp32 -> bf16 for W1, W3, Wih, Whh.
// 3,145,728 elements total; 8 per thread; grid 1536 x 256.
// ---------------------------------------------------------------------------
__global__ __launch_bounds__(256) void pack_kernel(
    const float* __restrict__ W1, const float* __restrict__ W3,
    const float* __restrict__ Wih, const float* __restrict__ Whh,
    __hip_bfloat16* __restrict__ W1b, __hip_bfloat16* __restrict__ W3b,
    __hip_bfloat16* __restrict__ Wihb, __hip_bfloat16* __restrict__ Whhb)
{
    const size_t e = ((size_t)blockIdx.x * 256 + threadIdx.x) * 8;
    const float* src; __hip_bfloat16* dst; size_t off;
    if (e < 524288)        { src = W1;  dst = W1b;  off = e; }
    else if (e < 1048576)  { src = W3;  dst = W3b;  off = e - 524288; }
    else if (e < 2097152)  { src = Wih; dst = Wihb; off = e - 1048576; }
    else                   { src = Whh; dst = Whhb; off = e - 2097152; }
#pragma unroll
    for (int j = 0; j < 8; ++j) dst[off + j] = __float2bfloat16(src[off + j]);
}

// ---------------------------------------------------------------------------
// Dual-input 64x64 MFMA GEMM tile:
//   C[m,n] = relu( sum_k A1[m,k]*W[n,k] + sum_k A2[m,k]*W[n,512+k] + bias[n] )
// A1,A2: [1024 x 512] bf16 row-major; W: [512 x 1024] bf16 row-major
// (K-contig); bias fp32. WG = 4 waves; wave w covers rows [tile_m+16w,+16).
// MFMA 16x16x32_bf16 layouts (HW-verified):
//   A-frag: lane l holds A[m=l&15][k=(l>>4)*8+j]
//   B-frag: lane l holds B[k=(l>>4)*8+j][n=l&15]  (= W[l&15][k], K-contig)
//   C/D:    lane l reg r -> row=(l>>4)*4+r, col=l&15
// ---------------------------------------------------------------------------
static __device__ __forceinline__ void gemm2_tile_64x64(
    const __hip_bfloat16* __restrict__ A1,
    const __hip_bfloat16* __restrict__ A2,
    const __hip_bfloat16* __restrict__ W,
    const float* __restrict__ bias,
    __hip_bfloat16* __restrict__ C,
    int tile_m, int tile_n)
{
    const int tid  = threadIdx.x;
    const int wave = tid >> 6;
    const int lane = tid & 63;
    const int l15  = lane & 15;
    const int quad = lane >> 4;

    const __hip_bfloat16* a1 = A1 + (size_t)(tile_m + wave * 16 + l15) * 512 + quad * 8;
    const __hip_bfloat16* a2 = A2 + (size_t)(tile_m + wave * 16 + l15) * 512 + quad * 8;
    const __hip_bfloat16* wr = W  + (size_t)(tile_n + l15) * 1024 + quad * 8;

    floatx4 acc0 = {0.f, 0.f, 0.f, 0.f};
    floatx4 acc1 = {0.f, 0.f, 0.f, 0.f};
    floatx4 acc2 = {0.f, 0.f, 0.f, 0.f};
    floatx4 acc3 = {0.f, 0.f, 0.f, 0.f};

    for (int k0 = 0; k0 < 512; k0 += 32) {          // phase 1: A1 * W[:, :512]
        bfrag8 a = load8(a1 + k0);
        acc0 = __builtin_amdgcn_mfma_f32_16x16x32_bf16(a, load8(wr + k0),                     acc0, 0, 0, 0);
        acc1 = __builtin_amdgcn_mfma_f32_16x16x32_bf16(a, load8(wr + (size_t)16 * 1024 + k0), acc1, 0, 0, 0);
        acc2 = __builtin_amdgcn_mfma_f32_16x16x32_bf16(a, load8(wr + (size_t)32 * 1024 + k0), acc2, 0, 0, 0);
        acc3 = __builtin_amdgcn_mfma_f32_16x16x32_bf16(a, load8(wr + (size_t)48 * 1024 + k0), acc3, 0, 0, 0);
    }
    for (int k0 = 0; k0 < 512; k0 += 32) {          // phase 2: A2 * W[:, 512:]
        bfrag8 a = load8(a2 + k0);
        acc0 = __builtin_amdgcn_mfma_f32_16x16x32_bf16(a, load8(wr + 512 + k0),                     acc0, 0, 0, 0);
        acc1 = __builtin_amdgcn_mfma_f32_16x16x32_bf16(a, load8(wr + (size_t)16 * 1024 + 512 + k0), acc1, 0, 0, 0);
        acc2 = __builtin_amdgcn_mfma_f32_16x16x32_bf16(a, load8(wr + (size_t)32 * 1024 + 512 + k0), acc2, 0, 0, 0);
        acc3 = __builtin_amdgcn_mfma_f32_16x16x32_bf16(a, load8(wr + (size_t)48 * 1024 + 512 + k0), acc3, 0, 0, 0);
    }

    const int row = tile_m + wave * 16 + quad * 4;
    floatx4 accs[4] = {acc0, acc1, acc2, acc3};
#pragma unroll
    for (int c = 0; c < 4; ++c) {
        const int col = tile_n + c * 16 + l15;
        const float bv = bias[col];
#pragma unroll
        for (int r = 0; r < 4; ++r) {
            float v = accs[c][r] + bv;
            v = fmaxf(v, 0.0f);  // relu
            C[(size_t)(row + r) * 512 + col] = __float2bfloat16(v);
        }
    }
}

// ---------------------------------------------------------------------------
// Stage 1: blocks [0,128):  z1 = relu(h_prev@W1[:,:512]^T + c@W1[:,512:]^T + b1)
//          blocks [128,640): z2 = relu(sv[:,t,:] @ W2^T + b2)   (fp32 GEMV)
// ---------------------------------------------------------------------------
__global__ __launch_bounds__(256) void stage1_kernel(
    const __hip_bfloat16* __restrict__ hprev, const __hip_bfloat16* __restrict__ cbf,
    const __hip_bfloat16* __restrict__ W1b, const float* __restrict__ b1,
    const float* __restrict__ sv, const float* __restrict__ W2, const float* __restrict__ b2,
    __hip_bfloat16* __restrict__ z1, __hip_bfloat16* __restrict__ z2, int t)
{
    if (blockIdx.x < 128) {
        const int bm = blockIdx.x >> 3;   // 0..15
        const int bn = blockIdx.x & 7;    // 0..7
        gemm2_tile_64x64(hprev, cbf, W1b, b1, z1, bm * 64, bn * 64);
    } else {
        const int idx = (blockIdx.x - 128) * 256 + threadIdx.x;  // 0..131071
        const int b  = idx >> 7;          // batch row
        const int n0 = (idx & 127) << 2;  // 4 outputs
        const float* svp = sv + ((size_t)b * T_SZ + t) * DPV;
        float sva[DPV];
#pragma unroll
        for (int k = 0; k < DPV; ++k) sva[k] = svp[k];
#pragma unroll
        for (int j = 0; j < 4; ++j) {
            const int n = n0 + j;
            const float* wrow = W2 + (size_t)n * DPV;
            float acc = b2[n];
#pragma unroll
            for (int k = 0; k < DPV; ++k) acc += sva[k] * wrow[k];
            z2[(size_t)b * 512 + n] = __float2bfloat16(fmaxf(acc, 0.0f));
        }
    }
}

// ---------------------------------------------------------------------------
// Stage 2: x = relu(z1 @ W3[:,:512]^T + z2 @ W3[:,512:]^T + b3)
// ---------------------------------------------------------------------------
__global__ __launch_bounds__(256) void stage2_kernel(
    const __hip_bfloat16* __restrict__ z1, const __hip_bfloat16* __restrict__ z2,
    const __hip_bfloat16* __restrict__ W3b, const float* __restrict__ b3,
    __hip_bfloat16* __restrict__ x)
{
    const int bm = blockIdx.x >> 3;
    const int bn = blockIdx.x & 7;
    gemm2_tile_64x64(z1, z2, W3b, b3, x, bm * 64, bn * 64);
}

// ---------------------------------------------------------------------------
// Stage 3: gates = x @ Wih^T + h_prev @ Whh^T + (bih+bhh); LSTM cell.
// grid 256 = 16(m-tiles of 64) x 16(j-tiles of 32). Wave: 16 rows,
// acc[gate 0..3][col-subtile 0..1]. Writes c32/cbf, h_new bf16 (ws),
// h_new fp32 into out[:,t,:]. Reads h_prev from a separate buffer.
// ---------------------------------------------------------------------------
__global__ __launch_bounds__(256) void stage3_kernel(
    const __hip_bfloat16* __restrict__ x, const __hip_bfloat16* __restrict__ hprev,
    const __hip_bfloat16* __restrict__ Wihb, const __hip_bfloat16* __restrict__ Whhb,
    const float* __restrict__ bih, const float* __restrict__ bhh,
    float* __restrict__ c32, __hip_bfloat16* __restrict__ cbf,
    __hip_bfloat16* __restrict__ hnew, float* __restrict__ out, int t)
{
    const int bm = blockIdx.x >> 4;   // 0..15
    const int bj = blockIdx.x & 15;   // 0..15
    const int tile_m = bm * 64;
    const int j0 = bj * 32;

    const int tid  = threadIdx.x;
    const int wave = tid >> 6;
    const int lane = tid & 63;
    const int l15  = lane & 15;
    const int quad = lane >> 4;

    const __hip_bfloat16* xrow = x     + (size_t)(tile_m + wave * 16 + l15) * 512 + quad * 8;
    const __hip_bfloat16* hrow = hprev + (size_t)(tile_m + wave * 16 + l15) * 512 + quad * 8;
    const __hip_bfloat16* wib  = Wihb  + (size_t)(j0 + l15) * 512 + quad * 8;
    const __hip_bfloat16* whb  = Whhb  + (size_t)(j0 + l15) * 512 + quad * 8;

    floatx4 acc[4][2];
#pragma unroll
    for (int g = 0; g < 4; ++g)
#pragma unroll
        for (int cb = 0; cb < 2; ++cb) acc[g][cb] = (floatx4){0.f, 0.f, 0.f, 0.f};

    for (int k0 = 0; k0 < 512; k0 += 32) {          // phase 1: x @ Wih^T
        bfrag8 a = load8(xrow + k0);
#pragma unroll
        for (int g = 0; g < 4; ++g)
#pragma unroll
            for (int cb = 0; cb < 2; ++cb) {
                bfrag8 b = load8(wib + (size_t)(g * 512 + cb * 16) * 512 + k0);
                acc[g][cb] = __builtin_amdgcn_mfma_f32_16x16x32_bf16(a, b, acc[g][cb], 0, 0, 0);
            }
    }
    for (int k0 = 0; k0 < 512; k0 += 32) {          // phase 2: h_prev @ Whh^T
        bfrag8 a = load8(hrow + k0);
#pragma unroll
        for (int g = 0; g < 4; ++g)
#pragma unroll
            for (int cb = 0; cb < 2; ++cb) {
                bfrag8 b = load8(whb + (size_t)(g * 512 + cb * 16) * 512 + k0);
                acc[g][cb] = __builtin_amdgcn_mfma_f32_16x16x32_bf16(a, b, acc[g][cb], 0, 0, 0);
            }
    }

    const int row = tile_m + wave * 16 + quad * 4;
#pragma unroll
    for (int cb = 0; cb < 2; ++cb) {
        const int j = j0 + cb * 16 + l15;
        const float bi = bih[j]        + bhh[j];
        const float bf = bih[512 + j]  + bhh[512 + j];
        const float bg = bih[1024 + j] + bhh[1024 + j];
        const float bo = bih[1536 + j] + bhh[1536 + j];
#pragma unroll
        for (int r = 0; r < 4; ++r) {
            const int rr = row + r;
            const float iv = sigm(acc[0][cb][r] + bi);
            const float fv = sigm(acc[1][cb][r] + bf);
            const float gv = tanhf(acc[2][cb][r] + bg);
            const float ov = sigm(acc[3][cb][r] + bo);
            const float cn = fv * c32[(size_t)rr * 512 + j] + iv * gv;
            const float hv = ov * tanhf(cn);
            c32[(size_t)rr * 512 + j] = cn;
            cbf[(size_t)rr * 512 + j] = __float2bfloat16(cn);
            hnew[(size_t)rr * 512 + j] = __float2bfloat16(hv);
            out[((size_t)rr * T_SZ + t) * H_SZ + j] = hv;   // fp32 output
        }
    }
}

// ---------------------------------------------------------------------------
// Workspace layout (14 MB):
//   0 MB  c32   fp32 [1024x512]  (2 MB)
//   2 MB  cbf   bf16 [1024x512]  (1 MB)
//   3 MB  z1    bf16 [1024x512]  (1 MB)
//   4 MB  z2    bf16 [1024x512]  (1 MB)
//   5 MB  x     bf16 [1024x512]  (1 MB)
//   6 MB  hA    bf16 [1024x512]  (1 MB)   h ping
//   7 MB  hB    bf16 [1024x512]  (1 MB)   h pong
//   8 MB  W1b   bf16 [512x1024]  (1 MB)
//   9 MB  W3b   bf16 [512x1024]  (1 MB)
//  10 MB  Wihb  bf16 [2048x512]  (2 MB)
//  12 MB  Whhb  bf16 [2048x512]  (2 MB)
// ---------------------------------------------------------------------------
extern "C" void kernel_launch(void* const* d_in, const int* in_sizes, int n_in,
                              void* d_out, int out_size, void* d_ws, size_t ws_size,
                              hipStream_t stream) {
    (void)in_sizes; (void)n_in; (void)out_size; (void)ws_size;

    const float* sv  = (const float*)d_in[0];
    const float* W1  = (const float*)d_in[1];
    const float* b1  = (const float*)d_in[2];
    const float* W2  = (const float*)d_in[3];
    const float* b2  = (const float*)d_in[4];
    const float* W3  = (const float*)d_in[5];
    const float* b3  = (const float*)d_in[6];
    const float* Wih = (const float*)d_in[7];
    const float* Whh = (const float*)d_in[8];
    const float* bih = (const float*)d_in[9];
    const float* bhh = (const float*)d_in[10];
    float* out = (float*)d_out;   // fp32 output per reference dtype

    char* w = (char*)d_ws;
    float*          c32  = (float*)         (w);
    __hip_bfloat16* cbf  = (__hip_bfloat16*)(w + (size_t)(2 << 20));
    __hip_bfloat16* z1   = (__hip_bfloat16*)(w + (size_t)(3 << 20));
    __hip_bfloat16* z2   = (__hip_bfloat16*)(w + (size_t)(4 << 20));
    __hip_bfloat16* x    = (__hip_bfloat16*)(w + (size_t)(5 << 20));
    __hip_bfloat16* hA   = (__hip_bfloat16*)(w + (size_t)(6 << 20));
    __hip_bfloat16* hB   = (__hip_bfloat16*)(w + (size_t)(7 << 20));
    __hip_bfloat16* W1b  = (__hip_bfloat16*)(w + (size_t)(8 << 20));
    __hip_bfloat16* W3b  = (__hip_bfloat16*)(w + (size_t)(9 << 20));
    __hip_bfloat16* Wihb = (__hip_bfloat16*)(w + (size_t)(10 << 20));
    __hip_bfloat16* Whhb = (__hip_bfloat16*)(w + (size_t)(12 << 20));

    hipMemsetAsync(c32, 0, (size_t)(2 << 20), stream);  // c0 = 0 (fp32 master)
    hipMemsetAsync(cbf, 0, (size_t)(1 << 20), stream);  // c0 = 0 (bf16 shadow)
    hipMemsetAsync(hA,  0, (size_t)(1 << 20), stream);  // h0 = 0

    pack_kernel<<<1536, 256, 0, stream>>>(W1, W3, Wih, Whh, W1b, W3b, Wihb, Whhb);

    for (int t = 0; t < T_SZ; ++t) {
        __hip_bfloat16* hprev = (t & 1) ? hB : hA;
        __hip_bfloat16* hnext = (t & 1) ? hA : hB;
        stage1_kernel<<<640, 256, 0, stream>>>(hprev, cbf, W1b, b1, sv, W2, b2, z1, z2, t);
        stage2_kernel<<<128, 256, 0, stream>>>(z1, z2, W3b, b3, x);
        stage3_kernel<<<256, 256, 0, stream>>>(x, hprev, Wihb, Whhb, bih, bhh,
                                               c32, cbf, hnext, out, t);
    }
}